// Round 1
// baseline (467.071 us; speedup 1.0000x reference)
//
#include <hip/hip_runtime.h>

constexpr int B_ = 256;
constexpr int N_ = 300;
constexpr int E_ = 100;
constexpr int ITILE = 32;
constexpr int NTI = 10;            // ceil(300/32)
constexpr int JT = 40;             // j-cols per wave tile
constexpr int SST = 32;            // S_T row stride (words)
constexpr int LDS_FLOATS = 30000 + 400 + 300 * SST + 32;  // h + A + S_T + rinv = 40032
constexpr float NEGINF = -9e15f;
constexpr float SLOPE = 0.2f;

__global__ __launch_bounds__(512, 2)
void gat_fused(const float* __restrict__ H, const int* __restrict__ ADJ,
               const float* __restrict__ A, float* __restrict__ OUT) {
  extern __shared__ float sm[];
  float* h_s  = sm;                       // [300][100]
  float* A_s  = sm + 30000;               // [4][100]
  float* S_T  = sm + 30400;               // [300][SST]  (transposed: [j][i_local])
  float* rinv = sm + 30400 + 300 * SST;   // [32]

  const int b    = blockIdx.x;
  const int tid  = threadIdx.x;
  const int w    = tid >> 6;     // wave 0..7
  const int lane = tid & 63;
  const int il   = lane >> 3;    // 0..7
  const int jl   = lane & 7;     // 0..7

  // ---- stage h[b] and A into LDS (coalesced float4) ----
  {
    const float4* src = reinterpret_cast<const float4*>(H + (size_t)b * (N_ * E_));
    float4* dst = reinterpret_cast<float4*>(h_s);
    for (int t = tid; t < (N_ * E_) / 4; t += 512) dst[t] = src[t];
    if (tid < (4 * E_) / 4)
      reinterpret_cast<float4*>(A_s)[tid] = reinterpret_cast<const float4*>(A)[tid];
  }
  __syncthreads();

  for (int it = 0; it < NTI; ++it) {
    const int i0 = it * ITILE;
    const int rows = min(ITILE, N_ - i0);   // 32 or 12 (always multiple of 4)

    // ---------- scores: wave w covers j in [40w, 40w+40), micro-tile 4i x 5j ----------
    {
      const int j0 = JT * w;
      int   aoff[4][5];
      bool  msk [4][5];
      float s   [4][5];
      int ia[4], ja[5];
#pragma unroll
      for (int a = 0; a < 4; ++a) ia[a] = min(i0 + il + 8 * a, N_ - 1);
#pragma unroll
      for (int c = 0; c < 5; ++c) ja[c] = min(j0 + jl + 8 * c, N_ - 1);
#pragma unroll
      for (int a = 0; a < 4; ++a) {
        const int i = i0 + il + 8 * a;
#pragma unroll
        for (int c = 0; c < 5; ++c) {
          const int j = j0 + jl + 8 * c;
          int k = 0;
          if (i < N_ && j < N_) k = ADJ[(i + b * N_) * N_ + j];
          msk[a][c]  = (k > 0);
          aoff[a][c] = (k > 0 ? k - 1 : 0) * E_;
          s[a][c] = 0.f;
        }
      }
      for (int d = 0; d < E_; d += 4) {
        float4 hi[4], hj[5];
#pragma unroll
        for (int a = 0; a < 4; ++a)
          hi[a] = *reinterpret_cast<const float4*>(&h_s[ia[a] * E_ + d]);
#pragma unroll
        for (int c = 0; c < 5; ++c)
          hj[c] = *reinterpret_cast<const float4*>(&h_s[ja[c] * E_ + d]);
#pragma unroll
        for (int a = 0; a < 4; ++a) {
#pragma unroll
          for (int c = 0; c < 5; ++c) {
            const float4 av = *reinterpret_cast<const float4*>(&A_s[aoff[a][c] + d]);
            float acc = s[a][c];
            acc = fmaf(hi[a].x * hj[c].x, av.x, acc);
            acc = fmaf(hi[a].y * hj[c].y, av.y, acc);
            acc = fmaf(hi[a].z * hj[c].z, av.z, acc);
            acc = fmaf(hi[a].w * hj[c].w, av.w, acc);
            s[a][c] = acc;
          }
        }
      }
#pragma unroll
      for (int a = 0; a < 4; ++a) {
        const int i = i0 + il + 8 * a;
#pragma unroll
        for (int c = 0; c < 5; ++c) {
          const int j = j0 + jl + 8 * c;
          if (i < N_ && j < N_) {
            const float v = s[a][c];
            S_T[j * SST + il + 8 * a] = msk[a][c] ? fmaxf(v, SLOPE * v) : NEGINF;
          }
        }
      }
    }
    __syncthreads();

    // ---------- softmax: store unnormalized exp(s-m), keep 1/sum ----------
    {
      const int r = tid >> 4;   // 0..31
      const int u = tid & 15;
      if (r < rows) {
        float m = -3.4e38f;
        for (int j = u; j < N_; j += 16) m = fmaxf(m, S_T[j * SST + r]);
#pragma unroll
        for (int off = 1; off < 16; off <<= 1) m = fmaxf(m, __shfl_xor(m, off));
        float sum = 0.f;
        for (int j = u; j < N_; j += 16) {
          const float e = __expf(S_T[j * SST + r] - m);
          S_T[j * SST + r] = e;
          sum += e;
        }
#pragma unroll
        for (int off = 1; off < 16; off <<= 1) sum += __shfl_xor(sum, off);
        if (u == 0) rinv[r] = 1.f / sum;
      }
    }
    __syncthreads();

    // ---------- PV: waves 0..3, 8 rows each; lane = (d-quad q, row-half rr) ----------
    if (w < 4) {
      const int q  = lane & 31;   // d-quad, q < 25 active
      const int rr = lane >> 5;   // 0/1
      const int r0 = 8 * w + 4 * rr;
      if (q < 25 && r0 < rows) {
        float acc[4][4];
#pragma unroll
        for (int x = 0; x < 4; ++x)
#pragma unroll
          for (int y = 0; y < 4; ++y) acc[x][y] = 0.f;
#pragma unroll 2
        for (int j = 0; j < N_; ++j) {
          const float4 hv = *reinterpret_cast<const float4*>(&h_s[j * E_ + 4 * q]);
          const float4 av = *reinterpret_cast<const float4*>(&S_T[j * SST + r0]);
          acc[0][0] = fmaf(av.x, hv.x, acc[0][0]);
          acc[0][1] = fmaf(av.x, hv.y, acc[0][1]);
          acc[0][2] = fmaf(av.x, hv.z, acc[0][2]);
          acc[0][3] = fmaf(av.x, hv.w, acc[0][3]);
          acc[1][0] = fmaf(av.y, hv.x, acc[1][0]);
          acc[1][1] = fmaf(av.y, hv.y, acc[1][1]);
          acc[1][2] = fmaf(av.y, hv.z, acc[1][2]);
          acc[1][3] = fmaf(av.y, hv.w, acc[1][3]);
          acc[2][0] = fmaf(av.z, hv.x, acc[2][0]);
          acc[2][1] = fmaf(av.z, hv.y, acc[2][1]);
          acc[2][2] = fmaf(av.z, hv.z, acc[2][2]);
          acc[2][3] = fmaf(av.z, hv.w, acc[2][3]);
          acc[3][0] = fmaf(av.w, hv.x, acc[3][0]);
          acc[3][1] = fmaf(av.w, hv.y, acc[3][1]);
          acc[3][2] = fmaf(av.w, hv.z, acc[3][2]);
          acc[3][3] = fmaf(av.w, hv.w, acc[3][3]);
        }
#pragma unroll
        for (int x = 0; x < 4; ++x) {
          const int i = i0 + r0 + x;
          const float sc = rinv[r0 + x];
          float4 o;
          o.x = acc[x][0] * sc;
          o.y = acc[x][1] * sc;
          o.z = acc[x][2] * sc;
          o.w = acc[x][3] * sc;
          *reinterpret_cast<float4*>(&OUT[(size_t)(i + b * N_) * E_ + 4 * q]) = o;
        }
      }
    }
    __syncthreads();
  }
}

extern "C" void kernel_launch(void* const* d_in, const int* in_sizes, int n_in,
                              void* d_out, int out_size, void* d_ws, size_t ws_size,
                              hipStream_t stream) {
  const float* H  = (const float*)d_in[0];
  const int*   AJ = (const int*)d_in[1];
  const float* A  = (const float*)d_in[2];
  float* OUT = (float*)d_out;

  (void)hipFuncSetAttribute(reinterpret_cast<const void*>(gat_fused),
                            hipFuncAttributeMaxDynamicSharedMemorySize,
                            LDS_FLOATS * 4);
  gat_fused<<<B_, 512, LDS_FLOATS * 4, stream>>>(H, AJ, A, OUT);
}

// Round 2
// 189.542 us; speedup vs baseline: 2.4642x; 2.4642x over previous
//
#include <hip/hip_runtime.h>

// ---- MFMA fragment-layout assumptions (gfx950, 16x16 family) ----
// A-frag (M=16,K=32): lane l holds A[row = l&15][k = (l>>4)*8 + e], e=0..7 (half8)
// B-frag (K=32,N=16): lane l holds B[k = (l>>4)*8 + e][col = l&15]
// C/D:               col = l&15, row = (l>>4)*4 + reg   [verified m89]
// K=16 variants: same with 4 elems, k = (l>>4)*4 + e.

typedef _Float16 half8 __attribute__((ext_vector_type(8)));
typedef _Float16 half4 __attribute__((ext_vector_type(4)));
typedef float f32x4 __attribute__((ext_vector_type(4)));

constexpr int B_ = 256;
constexpr int N_ = 300;
constexpr int E_ = 100;

constexpr int HS  = 120;   // h16 row stride (halves): 60 words, quad-step 15 (odd) -> 2-way free
constexpr int HTS = 304;   // hT row stride (halves)
constexpr int AS  = 312;   // alpha row stride (halves), 16B-aligned rows

constexpr float NEGINF = -9e15f;   // reference mask value
constexpr float PADV   = -3e38f;   // j-padding: exp -> 0 even vs NEGINF max

// LDS layout (bytes):
//   h16  [304][120] f16     @ 0        72960
//   hT   [112][304] f16     @ 72960    68096
//   alp  [ 32][312] f16     @ 141056   19968
//   A16  [  4][128] f16     @ 161024    1024
//   pbuf [  8][ 32] f32     @ 162048    1024
//   mrow [ 32]      f32     @ 163072     128
//   rinv [ 32]      f32     @ 163200     128
// total 163328 <= 163840
constexpr int LDS_BYTES = 163328;

__global__ __launch_bounds__(512, 2)
void gat_mfma(const float* __restrict__ H, const int* __restrict__ ADJ,
              const float* __restrict__ A, float* __restrict__ OUT) {
  extern __shared__ char smraw[];
  _Float16* h16 = (_Float16*)smraw;                // [304][120]
  _Float16* hT  = (_Float16*)(smraw + 72960);      // [112][304]
  _Float16* alp = (_Float16*)(smraw + 141056);     // [32][312]
  _Float16* A16 = (_Float16*)(smraw + 161024);     // [4][128]
  float* pbuf   = (float*)(smraw + 162048);        // [8][32]
  float* mrow   = (float*)(smraw + 163072);        // [32]
  float* rinv   = (float*)(smraw + 163200);        // [32]

  const int b    = blockIdx.x;
  const int tid  = threadIdx.x;
  const int w    = tid >> 6;
  const int lane = tid & 63;
  const int lg   = lane >> 4;   // 16-lane group 0..3
  const int ll   = lane & 15;

  const float* Hb = H + (size_t)b * (N_ * E_);

  // ---------------- stage h16 [j][d] (zero-padded 304 x 120) ----------------
  for (int u = tid; u < 304 * 15; u += 512) {
    const int j = u / 15, oct = u % 15;
    half8 v;
#pragma unroll
    for (int e = 0; e < 8; ++e) {
      const int d = oct * 8 + e;
      const float x = (j < N_ && d < E_) ? Hb[j * E_ + d] : 0.f;
      v[e] = (_Float16)x;
    }
    *(half8*)&h16[j * HS + oct * 8] = v;
  }
  // ---------------- stage hT [d][j] transposed (112 x 304) ----------------
  for (int u = tid; u < 112 * 76; u += 512) {
    const int d = u / 76, j0 = (u % 76) * 4;
    half4 v;
#pragma unroll
    for (int e = 0; e < 4; ++e) {
      const int j = j0 + e;
      const float x = (d < E_ && j < N_) ? Hb[j * E_ + d] : 0.f;
      v[e] = (_Float16)x;
    }
    *(half4*)&hT[d * HTS + j0] = v;
  }
  // ---------------- stage A16 [4][128] ----------------
  if (tid < 64) {
    const int k = tid >> 4, oct = tid & 15;
    half8 v;
#pragma unroll
    for (int e = 0; e < 8; ++e) {
      const int d = oct * 8 + e;
      v[e] = (_Float16)((d < E_) ? A[k * E_ + d] : 0.f);
    }
    *(half8*)&A16[k * 128 + oct * 8] = v;
  }
  __syncthreads();

  const int ntc = (w < 3) ? 3 : 2;   // j-tiles per wave: {w, w+8, w+16<19}
  const f32x4 vzero = {0.f, 0.f, 0.f, 0.f};

  for (int it = 0; it < 10; ++it) {
    const int i0 = it * 32;

    // ================= scores: e_k[i,j], all 4 k in AGPR accumulators ======
    f32x4 acc[3][2][4];
#pragma unroll
    for (int t = 0; t < 3; ++t)
#pragma unroll
      for (int m = 0; m < 2; ++m)
#pragma unroll
        for (int k = 0; k < 4; ++k) acc[t][m][k] = vzero;

#pragma unroll
    for (int db = 0; db < 3; ++db) {      // K blocks d = 0..95
      const int doct = db * 4 + lg;
      half8 a16[4];
#pragma unroll
      for (int k = 0; k < 4; ++k) a16[k] = *(half8*)&A16[k * 128 + doct * 8];
      half8 hA[2];
#pragma unroll
      for (int m = 0; m < 2; ++m)
        hA[m] = *(half8*)&h16[(i0 + m * 16 + ll) * HS + doct * 8];
      half8 bf[3];
#pragma unroll
      for (int t = 0; t < 3; ++t)
        if (t < ntc) bf[t] = *(half8*)&h16[((w + 8 * t) * 16 + ll) * HS + doct * 8];
#pragma unroll
      for (int m = 0; m < 2; ++m) {
#pragma unroll
        for (int k = 0; k < 4; ++k) {
          const half8 g = hA[m] * a16[k];   // G_k fragment: v_pk_mul_f16
#pragma unroll
          for (int t = 0; t < 3; ++t)
            if (t < ntc)
              acc[t][m][k] = __builtin_amdgcn_mfma_f32_16x16x32_f16(g, bf[t], acc[t][m][k], 0, 0, 0);
        }
      }
    }
    {   // K tail d = 96..111 (zeros past 100)
      half4 a16t[4];
#pragma unroll
      for (int k = 0; k < 4; ++k) a16t[k] = *(half4*)&A16[k * 128 + 96 + lg * 4];
      half4 hAt[2];
#pragma unroll
      for (int m = 0; m < 2; ++m)
        hAt[m] = *(half4*)&h16[(i0 + m * 16 + ll) * HS + 96 + lg * 4];
      half4 bt[3];
#pragma unroll
      for (int t = 0; t < 3; ++t)
        if (t < ntc) bt[t] = *(half4*)&h16[((w + 8 * t) * 16 + ll) * HS + 96 + lg * 4];
#pragma unroll
      for (int m = 0; m < 2; ++m)
#pragma unroll
        for (int k = 0; k < 4; ++k) {
          const half4 g = hAt[m] * a16t[k];
#pragma unroll
          for (int t = 0; t < 3; ++t)
            if (t < ntc)
              acc[t][m][k] = __builtin_amdgcn_mfma_f32_16x16x16f16(g, bt[t], acc[t][m][k], 0, 0, 0);
        }
    }

    // ============ select by adj + leaky-relu + mask (registers) ============
    float sv[3][2][4];
#pragma unroll
    for (int t = 0; t < 3; ++t)
      if (t < ntc) {
        const int j = (w + 8 * t) * 16 + ll;
#pragma unroll
        for (int m = 0; m < 2; ++m) {
#pragma unroll
          for (int r = 0; r < 4; ++r) {
            const int i = i0 + m * 16 + lg * 4 + r;
            float s;
            if (j >= N_) {
              s = PADV;                       // padding col: contributes exp=0
            } else {
              int a = 0;
              if (i < N_) a = ADJ[((size_t)b * N_ + i) * N_ + j];
              if (a == 0) {
                s = NEGINF;
              } else {
                const float e0 = acc[t][m][0][r], e1 = acc[t][m][1][r];
                const float e2 = acc[t][m][2][r], e3 = acc[t][m][3][r];
                const float e = (a == 1) ? e0 : (a == 2) ? e1 : (a == 3) ? e2 : e3;
                s = fmaxf(e, 0.2f * e);       // leaky relu
              }
            }
            sv[t][m][r] = s;
          }
        }
      }

    // ============ row max: shfl over 16-lane group, then cross-wave ========
#pragma unroll
    for (int m = 0; m < 2; ++m)
#pragma unroll
      for (int r = 0; r < 4; ++r) {
        float v = fmaxf(sv[0][m][r], sv[1][m][r]);
        if (ntc == 3) v = fmaxf(v, sv[2][m][r]);
#pragma unroll
        for (int o = 1; o < 16; o <<= 1) v = fmaxf(v, __shfl_xor(v, o));
        if (ll == 0) pbuf[w * 32 + m * 16 + lg * 4 + r] = v;
      }
    __syncthreads();
    if (tid < 32) {
      float v = pbuf[tid];
#pragma unroll
      for (int q = 1; q < 8; ++q) v = fmaxf(v, pbuf[q * 32 + tid]);
      mrow[tid] = v;
    }
    __syncthreads();

    // ============ exp + alpha16 write + row sum ============================
#pragma unroll
    for (int m = 0; m < 2; ++m)
#pragma unroll
      for (int r = 0; r < 4; ++r) {
        const int rloc = m * 16 + lg * 4 + r;
        const float mm = mrow[rloc];
        float sum = 0.f;
#pragma unroll
        for (int t = 0; t < 3; ++t)
          if (t < ntc) {
            const float p = __expf(sv[t][m][r] - mm);
            sum += p;
            alp[rloc * AS + (w + 8 * t) * 16 + ll] = (_Float16)p;
          }
#pragma unroll
        for (int o = 1; o < 16; o <<= 1) sum += __shfl_xor(sum, o);
        if (ll == 0) pbuf[w * 32 + rloc] = sum;
      }
    __syncthreads();
    if (tid < 32) {
      float v = 0.f;
#pragma unroll
      for (int q = 0; q < 8; ++q) v += pbuf[q * 32 + tid];
      rinv[tid] = 1.f / v;
    }
    __syncthreads();

    // ============ PV: out^T[e][i] = hT @ alpha^T ===========================
    // 14 (mt,nt) units over 8 waves: wave w -> (mt=w>>1, nt=w&1), and (+8) for w<6
    const int nu  = (w < 6) ? 2 : 1;
    const int ntp = w & 1;
    const int mt0 = w >> 1;
    const int mt1 = (w + 8) >> 1;
    f32x4 pa0 = vzero, pa1 = vzero;
#pragma unroll
    for (int jd = 0; jd < 9; ++jd) {
      const int j0 = jd * 32 + lg * 8;
      const half8 bfr = *(half8*)&alp[(ntp * 16 + ll) * AS + j0];
      const half8 a0 = *(half8*)&hT[(mt0 * 16 + ll) * HTS + j0];
      pa0 = __builtin_amdgcn_mfma_f32_16x16x32_f16(a0, bfr, pa0, 0, 0, 0);
      if (nu > 1) {
        const half8 a1 = *(half8*)&hT[(mt1 * 16 + ll) * HTS + j0];
        pa1 = __builtin_amdgcn_mfma_f32_16x16x32_f16(a1, bfr, pa1, 0, 0, 0);
      }
    }
    {   // j tail 288..303
      const int j0 = 288 + lg * 4;
      const half4 bt = *(half4*)&alp[(ntp * 16 + ll) * AS + j0];
      const half4 a0 = *(half4*)&hT[(mt0 * 16 + ll) * HTS + j0];
      pa0 = __builtin_amdgcn_mfma_f32_16x16x16f16(a0, bt, pa0, 0, 0, 0);
      if (nu > 1) {
        const half4 a1 = *(half4*)&hT[(mt1 * 16 + ll) * HTS + j0];
        pa1 = __builtin_amdgcn_mfma_f32_16x16x16f16(a1, bt, pa1, 0, 0, 0);
      }
    }
    // stores: out^T col = i (l&15), rows = e quad
    {
      const int iL = ntp * 16 + ll;
      const int i = i0 + iL;
      if (i < N_) {
        const float rv = rinv[iL];
        {
          const int e0 = mt0 * 16 + lg * 4;
          if (e0 < E_) {
            f32x4 o = pa0;
            o[0] *= rv; o[1] *= rv; o[2] *= rv; o[3] *= rv;
            *(f32x4*)&OUT[((size_t)b * N_ + i) * E_ + e0] = o;
          }
        }
        if (nu > 1) {
          const int e0 = mt1 * 16 + lg * 4;
          if (e0 < E_) {
            f32x4 o = pa1;
            o[0] *= rv; o[1] *= rv; o[2] *= rv; o[3] *= rv;
            *(f32x4*)&OUT[((size_t)b * N_ + i) * E_ + e0] = o;
          }
        }
      }
    }
    __syncthreads();
  }
}

extern "C" void kernel_launch(void* const* d_in, const int* in_sizes, int n_in,
                              void* d_out, int out_size, void* d_ws, size_t ws_size,
                              hipStream_t stream) {
  const float* H  = (const float*)d_in[0];
  const int*   AJ = (const int*)d_in[1];
  const float* A  = (const float*)d_in[2];
  float* OUT = (float*)d_out;

  (void)hipFuncSetAttribute(reinterpret_cast<const void*>(gat_mfma),
                            hipFuncAttributeMaxDynamicSharedMemorySize,
                            LDS_BYTES);
  gat_mfma<<<B_, 512, LDS_BYTES, stream>>>(H, AJ, A, OUT);
}

// Round 3
// 93.423 us; speedup vs baseline: 4.9995x; 2.0289x over previous
//
#include <hip/hip_runtime.h>

// ---- MFMA fragment layouts (gfx950, 16x16 family, verified m89) ----
// A-frag (M16,K32): lane l holds A[row=l&15][k=(l>>4)*8+e], e=0..7
// B-frag (K32,N16): lane l holds B[k=(l>>4)*8+e][col=l&15]
// C/D:              col=l&15, row=(l>>4)*4+reg
// K=16 variants: same with 4 elems, k=(l>>4)*4+e.
//
// Swapped scores: S^T = mfma(A=h_j, B=G_i), G_i[d][i]=h[i][d]*A_k[d]
//   -> lane holds S[i=ll][j=lg*4+r]  (4 j's of one i-row)
// PV: out^T = mfma(A=hT_frag, B=P): the score C-frag IS the PV B-frag. No
// transposes, no LDS P buffer, no barriers in the main loop.

typedef _Float16 half8 __attribute__((ext_vector_type(8)));
typedef _Float16 half4 __attribute__((ext_vector_type(4)));
typedef float f32x4 __attribute__((ext_vector_type(4)));

constexpr int B_ = 256, N_ = 300, E_ = 100;
constexpr int HS  = 120;   // h16 row stride (halves); 60 words, 28 mod 32 -> ~2-way free
constexpr int HTS = 312;   // hT row stride (halves); 156 words, 28 mod 32 -> ~2-way free
constexpr float NEGINF = -9e15f;   // reference mask value
constexpr float PADV   = -3e38f;   // padding: exp(PADV - anything) == 0, even vs NEGINF

// LDS: h16 [304][120] @0 (72960 B) | hT [112][312] @72960 (69888 B) | A16 [4][128] @142848 (1024 B)
constexpr int LDS_BYTES = 72960 + 69888 + 1024;   // 143872 <= 163840

__global__ __launch_bounds__(512, 2)
void gat_flash(const float* __restrict__ H, const int* __restrict__ ADJ,
               const float* __restrict__ A, float* __restrict__ OUT) {
  extern __shared__ char smraw[];
  _Float16* h16 = (_Float16*)smraw;                 // [304][HS]
  _Float16* hT  = (_Float16*)(smraw + 72960);       // [112][HTS]
  _Float16* A16 = (_Float16*)(smraw + 142848);      // [4][128]

  const int b    = blockIdx.x;
  const int tid  = threadIdx.x;
  const int w    = tid >> 6;
  const int lane = tid & 63;
  const int lg   = lane >> 4;   // 0..3
  const int ll   = lane & 15;

  const float* Hb  = H + (size_t)b * (N_ * E_);
  const int*   AJb = ADJ + (size_t)b * (N_ * N_);

  // ---------------- stage h16 [j][d], zero-padded 304x120 ----------------
  for (int u = tid; u < 304 * 15; u += 512) {
    const int j = u / 15, oct = u % 15;
    half8 v;
#pragma unroll
    for (int e = 0; e < 8; ++e) {
      const int d = oct * 8 + e;
      v[e] = (_Float16)((j < N_ && d < E_) ? Hb[j * E_ + d] : 0.f);
    }
    *(half8*)&h16[j * HS + oct * 8] = v;
  }
  // ---------------- stage hT [d][j], zero-padded 112x312 -----------------
  for (int u = tid; u < 112 * 76; u += 512) {
    const int d = u / 76, j0 = (u % 76) * 4;
    half4 v;
#pragma unroll
    for (int e = 0; e < 4; ++e) {
      const int j = j0 + e;
      v[e] = (_Float16)((d < E_ && j < N_) ? Hb[j * E_ + d] : 0.f);
    }
    *(half4*)&hT[d * HTS + j0] = v;
  }
  // ---------------- stage A16 [4][128] -----------------------------------
  if (tid < 64) {
    const int k = tid >> 4, oct = tid & 15;
    half8 v;
#pragma unroll
    for (int e = 0; e < 8; ++e) {
      const int d = oct * 8 + e;
      v[e] = (_Float16)((d < E_) ? A[k * E_ + d] : 0.f);
    }
    *(half8*)&A16[k * 128 + oct * 8] = v;
  }
  __syncthreads();   // the ONLY barrier

  // =============== per-wave independent i-strips (16 rows) ===============
  for (int s = w; s < 19; s += 8) {
    const int i0   = s * 16;
    const int irow = i0 + ll;              // this lane's output row (as MFMA col)
    const int irc  = min(irow, N_ - 1);

    // ---- G = h_i (.) A_k, per-strip registers (B-operand fragments) ----
    half8 g[3][4];
    half4 gt[4];
#pragma unroll
    for (int db = 0; db < 3; ++db) {
      const int e8 = db * 32 + lg * 8;
      const half8 hi = *(const half8*)&h16[irow * HS + e8];
#pragma unroll
      for (int k = 0; k < 4; ++k)
        g[db][k] = hi * *(const half8*)&A16[k * 128 + e8];
    }
    {
      const int e4 = 96 + lg * 4;
      const half4 hit = *(const half4*)&h16[irow * HS + e4];
#pragma unroll
      for (int k = 0; k < 4; ++k)
        gt[k] = hit * *(const half4*)&A16[k * 128 + e4];
    }

    float m = PADV, lsum = 0.f;
    f32x4 acc[7];
#pragma unroll
    for (int t = 0; t < 7; ++t) acc[t] = (f32x4){0.f, 0.f, 0.f, 0.f};

    const int* ajrow = AJb + (size_t)irc * N_;
    int4 av = *(const int4*)(ajrow + lg * 4);      // j-tile 0 chunk

    for (int jt = 0; jt < 19; ++jt) {
      const int j0 = jt * 16;
      // prefetch next tile's adj chunk (clamped; lg==3 @ jt==18 is overridden)
      int4 avn = av;
      if (jt < 18) {
        int jc = j0 + 16 + lg * 4;
        if (jc > N_ - 4) jc = N_ - 4;
        avn = *(const int4*)(ajrow + jc);
      }

      // ---- scores: S^T tile, 4 edge-type accumulators ----
      f32x4 c0 = {0.f,0.f,0.f,0.f}, c1 = c0, c2 = c0, c3 = c0;
      const int jrow = j0 + ll;
#pragma unroll
      for (int db = 0; db < 3; ++db) {
        const half8 aj = *(const half8*)&h16[jrow * HS + db * 32 + lg * 8];
        c0 = __builtin_amdgcn_mfma_f32_16x16x32_f16(aj, g[db][0], c0, 0, 0, 0);
        c1 = __builtin_amdgcn_mfma_f32_16x16x32_f16(aj, g[db][1], c1, 0, 0, 0);
        c2 = __builtin_amdgcn_mfma_f32_16x16x32_f16(aj, g[db][2], c2, 0, 0, 0);
        c3 = __builtin_amdgcn_mfma_f32_16x16x32_f16(aj, g[db][3], c3, 0, 0, 0);
      }
      {
        const half4 ajt = *(const half4*)&h16[jrow * HS + 96 + lg * 4];
        c0 = __builtin_amdgcn_mfma_f32_16x16x16f16(ajt, gt[0], c0, 0, 0, 0);
        c1 = __builtin_amdgcn_mfma_f32_16x16x16f16(ajt, gt[1], c1, 0, 0, 0);
        c2 = __builtin_amdgcn_mfma_f32_16x16x16f16(ajt, gt[2], c2, 0, 0, 0);
        c3 = __builtin_amdgcn_mfma_f32_16x16x16f16(ajt, gt[3], c3, 0, 0, 0);
      }

      // ---- PV A-operand fragments: issue early, consumed after softmax ----
      half4 hf[7];
#pragma unroll
      for (int t = 0; t < 7; ++t)
        hf[t] = *(const half4*)&hT[(t * 16 + ll) * HTS + j0 + lg * 4];

      // ---- select by adj + leaky-relu + mask (registers) ----
      const int va[4] = {av.x, av.y, av.z, av.w};
      float sv[4];
#pragma unroll
      for (int r = 0; r < 4; ++r) {
        const float e = (va[r] == 1) ? c0[r] : (va[r] == 2) ? c1[r]
                       : (va[r] == 3) ? c2[r] : c3[r];
        sv[r] = (va[r] == 0) ? NEGINF : fmaxf(e, 0.2f * e);
      }
      if (jt == 18 && lg == 3) { sv[0] = PADV; sv[1] = PADV; sv[2] = PADV; sv[3] = PADV; }

      // ---- online softmax (m shared across the 4 lane-groups of this i) ----
      float tmax = fmaxf(fmaxf(sv[0], sv[1]), fmaxf(sv[2], sv[3]));
      tmax = fmaxf(tmax, __shfl_xor(tmax, 16));
      tmax = fmaxf(tmax, __shfl_xor(tmax, 32));
      if (tmax > m) {
        const float f = __expf(m - tmax);
        m = tmax;
        lsum *= f;
#pragma unroll
        for (int t = 0; t < 7; ++t) {
          acc[t][0] *= f; acc[t][1] *= f; acc[t][2] *= f; acc[t][3] *= f;
        }
      }
      const float p0 = __expf(sv[0] - m), p1 = __expf(sv[1] - m);
      const float p2 = __expf(sv[2] - m), p3 = __expf(sv[3] - m);
      lsum += (p0 + p1) + (p2 + p3);
      half4 pb;
      pb[0] = (_Float16)p0; pb[1] = (_Float16)p1;
      pb[2] = (_Float16)p2; pb[3] = (_Float16)p3;
      av = avn;

      // ---- PV: acc[e-tile] += hT_frag x P ----
#pragma unroll
      for (int t = 0; t < 7; ++t)
        acc[t] = __builtin_amdgcn_mfma_f32_16x16x16f16(hf[t], pb, acc[t], 0, 0, 0);
    }

    // ---- epilogue: normalize + store ----
    lsum += __shfl_xor(lsum, 16);
    lsum += __shfl_xor(lsum, 32);
    const float rv = 1.f / lsum;
    if (irow < N_) {
      float* orow = OUT + ((size_t)b * N_ + irow) * E_;
#pragma unroll
      for (int t = 0; t < 7; ++t) {
        const int e0 = t * 16 + lg * 4;
        if (e0 < E_) {
          f32x4 o = acc[t];
          o[0] *= rv; o[1] *= rv; o[2] *= rv; o[3] *= rv;
          *(f32x4*)&orow[e0] = o;
        }
      }
    }
  }
}

extern "C" void kernel_launch(void* const* d_in, const int* in_sizes, int n_in,
                              void* d_out, int out_size, void* d_ws, size_t ws_size,
                              hipStream_t stream) {
  const float* H  = (const float*)d_in[0];
  const int*   AJ = (const int*)d_in[1];
  const float* A  = (const float*)d_in[2];
  float* OUT = (float*)d_out;

  (void)hipFuncSetAttribute(reinterpret_cast<const void*>(gat_flash),
                            hipFuncAttributeMaxDynamicSharedMemorySize,
                            LDS_BYTES);
  gat_flash<<<B_, 512, LDS_BYTES, stream>>>(H, AJ, A, OUT);
}